// Round 1
// baseline (824.326 us; speedup 1.0000x reference)
//
#include <hip/hip_runtime.h>
#include <hip/hip_bf16.h>
#include <stdint.h>

#define BATCH 128
#define CIN   256
#define CCAT  512
#define HH    24
#define WW    24
#define HP    26
#define WP    26
#define COUT  256
#define KDIM  4608   // 9*512
#define NPIX  576    // 24*24
#define MDIM  73728  // 128*576
#define NORD  25

typedef __attribute__((ext_vector_type(8))) short bf16x8;
typedef __attribute__((ext_vector_type(4))) float f32x4;

__device__ __forceinline__ unsigned short f2bf(float v) {
    union { float f; unsigned u; } x; x.f = v;
    unsigned r = x.u + 0x7fffu + ((x.u >> 16) & 1u);
    return (unsigned short)(r >> 16);
}
__device__ __forceinline__ float bf_lo(unsigned w) {
    union { unsigned u; float f; } x; x.u = w << 16; return x.f;
}
__device__ __forceinline__ float bf_hi(unsigned w) {
    union { unsigned u; float f; } x; x.u = w & 0xffff0000u; return x.f;
}

__device__ __forceinline__ void async_copy16(const void* gsrc, void* ldst) {
    __builtin_amdgcn_global_load_lds(
        (const __attribute__((address_space(1))) unsigned int*)gsrc,
        (__attribute__((address_space(3))) unsigned int*)ldst, 16, 0, 0);
}

// --- K0a: concat + pad(1) + NCHW->NHWC + fp32->bf16 ----------------------
__global__ __launch_bounds__(256) void prep_input(
        const float* __restrict__ src, const float* __restrict__ det,
        unsigned short* __restrict__ apad) {
    long idx = (long)blockIdx.x * 256 + threadIdx.x;   // one 8-channel chunk
    int c8 = (int)(idx & 63);
    long t = idx >> 6;
    int xx = (int)(t % WP); t /= WP;
    int yy = (int)(t % HP);
    int b  = (int)(t / HP);
    unsigned short o[8];
    if (yy == 0 || yy == HP - 1 || xx == 0 || xx == WP - 1) {
        #pragma unroll
        for (int j = 0; j < 8; j++) o[j] = 0;
    } else {
        int y = yy - 1, x = xx - 1;
        int c0 = c8 * 8;
        #pragma unroll
        for (int j = 0; j < 8; j++) {
            int cc = c0 + j;
            float v = (cc < CIN)
                ? src[(((long)b * CIN + cc) * HH + y) * WW + x]
                : det[(((long)b * CIN + (cc - CIN)) * HH + y) * WW + x];
            o[j] = f2bf(v);
        }
    }
    uint4 w;
    w.x = (unsigned)o[0] | ((unsigned)o[1] << 16);
    w.y = (unsigned)o[2] | ((unsigned)o[3] << 16);
    w.z = (unsigned)o[4] | ((unsigned)o[5] << 16);
    w.w = (unsigned)o[6] | ((unsigned)o[7] << 16);
    *(uint4*)(apad + idx * 8) = w;
}

// --- K0b: w1 OIHW -> B^T [N=256][K=4608] bf16; fold BN+bias --------------
__global__ __launch_bounds__(256) void prep_w(
        const float* __restrict__ w1, const float* __restrict__ b1,
        const float* __restrict__ gam, const float* __restrict__ bet,
        const float* __restrict__ mu, const float* __restrict__ var,
        unsigned short* __restrict__ bt,
        float* __restrict__ scale, float* __restrict__ shift) {
    int idx = blockIdx.x * 256 + threadIdx.x;
    if (idx < COUT * KDIM) {
        int n = idx / KDIM;
        int k = idx - n * KDIM;
        int s = k >> 9;          // (ky*3+kx)
        int ci = k & 511;
        int ky = s / 3, kx = s - ky * 3;
        float v = w1[(((long)n * 512 + ci) * 3 + ky) * 3 + kx];
        bt[idx] = f2bf(v);
    }
    if (blockIdx.x == 0 && threadIdx.x < COUT) {
        int c = threadIdx.x;
        float inv = gam[c] * rsqrtf(var[c] + 1e-5f);
        scale[c] = inv;
        shift[c] = (b1[c] - mu[c]) * inv + bet[c];
    }
}

// --- K1: implicit-GEMM conv1 + BN + ReLU, bf16 MFMA ----------------------
// C[M=73728][N=256] = A_im2col[M][4608] x B[4608][256]
__global__ __launch_bounds__(256) void conv1_gemm(
        const unsigned short* __restrict__ apad,
        const unsigned short* __restrict__ bt,
        const float* __restrict__ scale, const float* __restrict__ shift,
        unsigned short* __restrict__ xout) {
    __shared__ unsigned short smA[128 * 64];
    __shared__ unsigned short smB[128 * 64];
    int bid = blockIdx.x;
    int nb = bid & 1;
    int mb = bid >> 1;
    int m0 = mb * 128;
    int n0 = nb * 128;
    int tid = threadIdx.x;
    int wave = tid >> 6, lane = tid & 63;
    int lrow = lane >> 3;            // 0..7
    int lcol = (lane & 7) * 8;       // 0,8,..,56

    long apix[4];
    long brow[4];
    #pragma unroll
    for (int i = 0; i < 4; i++) {
        int row = (i * 4 + wave) * 8 + lrow;
        int m = m0 + row;
        int b = m / NPIX;
        int r = m - b * NPIX;
        int y = r / WW, x = r - y * WW;
        apix[i] = (((long)b * HP + y) * WP + x) * (long)CCAT + lcol;
        brow[i] = (long)(n0 + row) * KDIM + lcol;
    }

    f32x4 acc[4][4];
    #pragma unroll
    for (int i = 0; i < 4; i++)
        #pragma unroll
        for (int j = 0; j < 4; j++) acc[i][j] = (f32x4){0.f, 0.f, 0.f, 0.f};

    int wr = wave >> 1, wc = wave & 1;
    int fr = lane & 15;
    int fk = (lane >> 4) * 8;

    for (int ks = 0; ks < 72; ks++) {
        int seg = ks >> 3;
        int ky = seg / 3, kx = seg - ky * 3;
        int ci0 = (ks & 7) * 64;
        long segoff = (long)(ky * WP + kx) * CCAT + ci0;
        long koff = (long)ks * 64;
        #pragma unroll
        for (int i = 0; i < 4; i++)
            async_copy16(apad + apix[i] + segoff, (void*)&smA[(i * 4 + wave) * 512]);
        #pragma unroll
        for (int i = 0; i < 4; i++)
            async_copy16(bt + brow[i] + koff, (void*)&smB[(i * 4 + wave) * 512]);
        __syncthreads();
        #pragma unroll
        for (int kk = 0; kk < 2; kk++) {
            bf16x8 af[4], bfr[4];
            #pragma unroll
            for (int m = 0; m < 4; m++) {
                int row = wr * 64 + m * 16 + fr;
                af[m] = *(const bf16x8*)&smA[row * 64 + kk * 32 + fk];
            }
            #pragma unroll
            for (int n = 0; n < 4; n++) {
                int row = wc * 64 + n * 16 + fr;
                bfr[n] = *(const bf16x8*)&smB[row * 64 + kk * 32 + fk];
            }
            #pragma unroll
            for (int m = 0; m < 4; m++)
                #pragma unroll
                for (int n = 0; n < 4; n++)
                    acc[m][n] = __builtin_amdgcn_mfma_f32_16x16x32_bf16(
                        af[m], bfr[n], acc[m][n], 0, 0, 0);
        }
        __syncthreads();
    }

    int crow0 = (lane >> 4) * 4;
    #pragma unroll
    for (int n = 0; n < 4; n++) {
        int col = n0 + wc * 64 + n * 16 + fr;
        float sc = scale[col], sh = shift[col];
        #pragma unroll
        for (int m = 0; m < 4; m++) {
            int rbase = m0 + wr * 64 + m * 16 + crow0;
            #pragma unroll
            for (int j = 0; j < 4; j++) {
                float v = acc[m][n][j] * sc + sh;
                v = v > 0.f ? v : 0.f;
                xout[(long)(rbase + j) * COUT + col] = f2bf(v);
            }
        }
    }
}

// --- K2: 1x1 conv (256->25) + bias + softmax -> kmaps [pix][25] ----------
__global__ __launch_bounds__(256) void conv2_softmax(
        const unsigned short* __restrict__ x, const float* __restrict__ w2,
        const float* __restrict__ b2, float* __restrict__ kmaps) {
    __shared__ float w2s[NORD * 256];
    __shared__ float b2s[NORD];
    for (int i = threadIdx.x; i < NORD * 256; i += 256) w2s[i] = w2[i];
    if (threadIdx.x < NORD) b2s[threadIdx.x] = b2[threadIdx.x];
    __syncthreads();
    long pix = (long)blockIdx.x * 256 + threadIdx.x;
    float acc[NORD];
    #pragma unroll
    for (int o = 0; o < NORD; o++) acc[o] = b2s[o];
    const unsigned short* xr = x + pix * COUT;
    for (int kc = 0; kc < 32; kc++) {
        uint4 raw = *(const uint4*)(xr + kc * 8);
        float xf[8];
        xf[0] = bf_lo(raw.x); xf[1] = bf_hi(raw.x);
        xf[2] = bf_lo(raw.y); xf[3] = bf_hi(raw.y);
        xf[4] = bf_lo(raw.z); xf[5] = bf_hi(raw.z);
        xf[6] = bf_lo(raw.w); xf[7] = bf_hi(raw.w);
        #pragma unroll
        for (int o = 0; o < NORD; o++) {
            const float* wrow = &w2s[o * 256 + kc * 8];
            float4 wa = *(const float4*)(wrow);
            float4 wb = *(const float4*)(wrow + 4);
            acc[o] += xf[0] * wa.x + xf[1] * wa.y + xf[2] * wa.z + xf[3] * wa.w
                    + xf[4] * wb.x + xf[5] * wb.y + xf[6] * wb.z + xf[7] * wb.w;
        }
    }
    float mx = acc[0];
    #pragma unroll
    for (int o = 1; o < NORD; o++) mx = fmaxf(mx, acc[o]);
    float s = 0.f;
    #pragma unroll
    for (int o = 0; o < NORD; o++) { acc[o] = expf(acc[o] - mx); s += acc[o]; }
    float inv = 1.f / s;
    float* kout = kmaps + pix * NORD;
    #pragma unroll
    for (int o = 0; o < NORD; o++) kout[o] = acc[o] * inv;
}

// --- K3: 25-tap weighted propagation -------------------------------------
__global__ __launch_bounds__(576) void propagate(
        const float* __restrict__ src, const float* __restrict__ kmaps,
        float* __restrict__ out) {
    __shared__ float sm[28 * 28];
    int b  = blockIdx.y;
    int cg = blockIdx.x;         // 16 channels per block
    int tid = threadIdx.x;       // pixel id 0..575
    int y = tid / 24, x = tid - y * 24;
    float km[NORD];
    const float* kp = kmaps + ((long)b * NPIX + tid) * NORD;
    #pragma unroll
    for (int o = 0; o < NORD; o++) km[o] = kp[o];
    for (int c = 0; c < 16; c++) {
        int cc = cg * 16 + c;
        const float* sp = src + ((long)b * CIN + cc) * NPIX;
        __syncthreads();
        for (int t = tid; t < 28 * 28; t += 576) {
            int yy = t / 28, xx = t - yy * 28;
            float v = 0.f;
            if (yy >= 2 && yy < 26 && xx >= 2 && xx < 26)
                v = sp[(yy - 2) * 24 + (xx - 2)];
            sm[t] = v;
        }
        __syncthreads();
        float a = 0.f;
        #pragma unroll
        for (int o = 0; o < NORD; o++) {
            int dy = o / 5 - 2, dx = o % 5 - 2;
            a += km[o] * sm[(y + 2 + dy) * 28 + (x + 2 + dx)];
        }
        out[((long)b * CIN + cc) * NPIX + tid] = a;
    }
}

extern "C" void kernel_launch(void* const* d_in, const int* in_sizes, int n_in,
                              void* d_out, int out_size, void* d_ws, size_t ws_size,
                              hipStream_t stream) {
    const float* src = (const float*)d_in[0];
    const float* det = (const float*)d_in[1];
    const float* w1  = (const float*)d_in[2];
    const float* b1  = (const float*)d_in[3];
    const float* gam = (const float*)d_in[4];
    const float* bet = (const float*)d_in[5];
    const float* mu  = (const float*)d_in[6];
    const float* var = (const float*)d_in[7];
    const float* w2  = (const float*)d_in[8];
    const float* b2  = (const float*)d_in[9];
    float* out = (float*)d_out;

    char* ws = (char*)d_ws;
    size_t off = 0;
    unsigned short* apad = (unsigned short*)(ws + off); off += (size_t)BATCH * HP * WP * CCAT * 2;   // 88,604,672
    unsigned short* bt   = (unsigned short*)(ws + off); off += (size_t)COUT * KDIM * 2;              //  2,359,296
    unsigned short* xbuf = (unsigned short*)(ws + off); off += (size_t)MDIM * COUT * 2;              // 37,748,736
    float* kmaps = (float*)(ws + off); off += (size_t)MDIM * NORD * 4;                               //  7,372,800
    float* scale = (float*)(ws + off); off += 1024;
    float* shift = (float*)(ws + off); off += 1024;

    prep_input<<<21632, 256, 0, stream>>>(src, det, apad);
    prep_w<<<4608, 256, 0, stream>>>(w1, b1, gam, bet, mu, var, bt, scale, shift);
    conv1_gemm<<<1152, 256, 0, stream>>>(apad, bt, scale, shift, xbuf);
    conv2_softmax<<<288, 256, 0, stream>>>(xbuf, w2, b2, kmaps);
    propagate<<<dim3(16, 128), 576, 0, stream>>>(src, kmaps, out);
}

// Round 2
// 492.878 us; speedup vs baseline: 1.6725x; 1.6725x over previous
//
#include <hip/hip_runtime.h>
#include <hip/hip_bf16.h>
#include <stdint.h>

#define BATCH 128
#define CIN   256
#define CCAT  512
#define HH    24
#define WW    24
#define HP    26
#define WP    26
#define COUT  256
#define KDIM  4608   // 9*512
#define NPIX  576    // 24*24
#define MDIM  73728  // 128*576
#define NORD  25

typedef __attribute__((ext_vector_type(8))) short bf16x8;
typedef __attribute__((ext_vector_type(4))) float f32x4;

__device__ __forceinline__ unsigned short f2bf(float v) {
    union { float f; unsigned u; } x; x.f = v;
    unsigned r = x.u + 0x7fffu + ((x.u >> 16) & 1u);
    return (unsigned short)(r >> 16);
}
__device__ __forceinline__ float bf_lo(unsigned w) {
    union { unsigned u; float f; } x; x.u = w << 16; return x.f;
}
__device__ __forceinline__ float bf_hi(unsigned w) {
    union { unsigned u; float f; } x; x.u = w & 0xffff0000u; return x.f;
}

__device__ __forceinline__ void async_copy16(const void* gsrc, void* ldst) {
    __builtin_amdgcn_global_load_lds(
        (const __attribute__((address_space(1))) unsigned int*)gsrc,
        (__attribute__((address_space(3))) unsigned int*)ldst, 16, 0, 0);
}

// --- K0a: coalesced NCHW fp32 -> padded NHWC bf16 via LDS transpose ------
// block = (pixel-tile pt in [0,3), channel-group cg in [0,8), batch b)
// read:  lanes walk pixels  (coalesced 4B*64 = 256B lines per channel)
// write: lanes walk channels (128B contiguous per pixel in NHWC)
#define PTILE 192
#define LSTR  72   // shorts; stride 72 -> bank step 4 -> 2-way (free)
__global__ __launch_bounds__(256) void prep_transpose(
        const float* __restrict__ src, const float* __restrict__ det,
        unsigned short* __restrict__ apad) {
    __shared__ unsigned short lds[PTILE * LSTR];
    int pt = blockIdx.x;
    int cg = blockIdx.y;
    int b  = blockIdx.z;
    int c0 = cg * 64;
    int p0 = pt * PTILE;
    const float* inp = (c0 < CIN)
        ? (src + ((long)b * CIN + c0) * NPIX)
        : (det + ((long)b * CIN + (c0 - CIN)) * NPIX);
    int tid = threadIdx.x;

    // read phase: 64ch x 192px, thread = 4 consecutive channels x 1 pixel
    #pragma unroll
    for (int it = 0; it < 12; it++) {
        int l  = it * 256 + tid;        // 0..3071
        int cq = l / PTILE;             // 0..15 (4-channel quad)
        int px = l - cq * PTILE;        // 0..191
        const float* pb = inp + (long)cq * 4 * NPIX + p0 + px;
        unsigned short v0 = f2bf(pb[0 * NPIX]);
        unsigned short v1 = f2bf(pb[1 * NPIX]);
        unsigned short v2 = f2bf(pb[2 * NPIX]);
        unsigned short v3 = f2bf(pb[3 * NPIX]);
        uint2 w;
        w.x = (unsigned)v0 | ((unsigned)v1 << 16);
        w.y = (unsigned)v2 | ((unsigned)v3 << 16);
        *(uint2*)&lds[px * LSTR + cq * 4] = w;
    }
    __syncthreads();

    // write phase: thread = 8 channels x 1 pixel, uint4 (16B) stores
    #pragma unroll
    for (int it = 0; it < 6; it++) {
        int l   = it * 256 + tid;       // 0..1535
        int px  = l >> 3;               // 0..191
        int ch8 = l & 7;
        uint4 w = *(const uint4*)&lds[px * LSTR + ch8 * 8];
        int p  = p0 + px;
        int y  = p / WW, x = p - y * WW;
        long o = (((long)b * HP + (y + 1)) * WP + (x + 1)) * CCAT + c0 + ch8 * 8;
        *(uint4*)(apad + o) = w;
    }
}

// --- K0a': zero the 1-wide halo of the padded NHWC buffer ---------------
__global__ __launch_bounds__(256) void zero_halo(unsigned short* __restrict__ apad) {
    int t = blockIdx.x * 256 + threadIdx.x;   // 128*100*64
    int ch8 = t & 63;
    int r   = t >> 6;
    int hp  = r % 100;
    int b   = r / 100;
    int y, x;
    if (hp < 26)      { y = 0;       x = hp; }
    else if (hp < 52) { y = 25;      x = hp - 26; }
    else if (hp < 76) { y = hp - 51; x = 0; }
    else              { y = hp - 75; x = 25; }
    long o = (((long)b * HP + y) * WP + x) * CCAT + ch8 * 8;
    *(uint4*)(apad + o) = (uint4){0u, 0u, 0u, 0u};
}

// --- K0b: w1 OIHW -> B^T [N=256][K=4608] bf16; fold BN+bias --------------
__global__ __launch_bounds__(256) void prep_w(
        const float* __restrict__ w1, const float* __restrict__ b1,
        const float* __restrict__ gam, const float* __restrict__ bet,
        const float* __restrict__ mu, const float* __restrict__ var,
        unsigned short* __restrict__ bt,
        float* __restrict__ scale, float* __restrict__ shift) {
    int idx = blockIdx.x * 256 + threadIdx.x;
    if (idx < COUT * KDIM) {
        int n = idx / KDIM;
        int k = idx - n * KDIM;
        int s = k >> 9;          // (ky*3+kx)
        int ci = k & 511;
        int ky = s / 3, kx = s - ky * 3;
        float v = w1[(((long)n * 512 + ci) * 3 + ky) * 3 + kx];
        bt[idx] = f2bf(v);
    }
    if (blockIdx.x == 0 && threadIdx.x < COUT) {
        int c = threadIdx.x;
        float inv = gam[c] * rsqrtf(var[c] + 1e-5f);
        scale[c] = inv;
        shift[c] = (b1[c] - mu[c]) * inv + bet[c];
    }
}

// --- K1: implicit-GEMM conv1 + BN + ReLU, bf16 MFMA ----------------------
// C[M=73728][N=256] = A_im2col[M][4608] x B[4608][256]
__global__ __launch_bounds__(256) void conv1_gemm(
        const unsigned short* __restrict__ apad,
        const unsigned short* __restrict__ bt,
        const float* __restrict__ scale, const float* __restrict__ shift,
        unsigned short* __restrict__ xout) {
    __shared__ unsigned short smA[128 * 64];
    __shared__ unsigned short smB[128 * 64];
    int bid = blockIdx.x;
    int nb = bid & 1;
    int mb = bid >> 1;
    int m0 = mb * 128;
    int n0 = nb * 128;
    int tid = threadIdx.x;
    int wave = tid >> 6, lane = tid & 63;
    int lrow = lane >> 3;            // 0..7
    int lcol = (lane & 7) * 8;       // 0,8,..,56

    long apix[4];
    long brow[4];
    #pragma unroll
    for (int i = 0; i < 4; i++) {
        int row = (i * 4 + wave) * 8 + lrow;
        int m = m0 + row;
        int b = m / NPIX;
        int r = m - b * NPIX;
        int y = r / WW, x = r - y * WW;
        apix[i] = (((long)b * HP + y) * WP + x) * (long)CCAT + lcol;
        brow[i] = (long)(n0 + row) * KDIM + lcol;
    }

    f32x4 acc[4][4];
    #pragma unroll
    for (int i = 0; i < 4; i++)
        #pragma unroll
        for (int j = 0; j < 4; j++) acc[i][j] = (f32x4){0.f, 0.f, 0.f, 0.f};

    int wr = wave >> 1, wc = wave & 1;
    int fr = lane & 15;
    int fk = (lane >> 4) * 8;

    for (int ks = 0; ks < 72; ks++) {
        int seg = ks >> 3;
        int ky = seg / 3, kx = seg - ky * 3;
        int ci0 = (ks & 7) * 64;
        long segoff = (long)(ky * WP + kx) * CCAT + ci0;
        long koff = (long)ks * 64;
        #pragma unroll
        for (int i = 0; i < 4; i++)
            async_copy16(apad + apix[i] + segoff, (void*)&smA[(i * 4 + wave) * 512]);
        #pragma unroll
        for (int i = 0; i < 4; i++)
            async_copy16(bt + brow[i] + koff, (void*)&smB[(i * 4 + wave) * 512]);
        __syncthreads();
        #pragma unroll
        for (int kk = 0; kk < 2; kk++) {
            bf16x8 af[4], bfr[4];
            #pragma unroll
            for (int m = 0; m < 4; m++) {
                int row = wr * 64 + m * 16 + fr;
                af[m] = *(const bf16x8*)&smA[row * 64 + kk * 32 + fk];
            }
            #pragma unroll
            for (int n = 0; n < 4; n++) {
                int row = wc * 64 + n * 16 + fr;
                bfr[n] = *(const bf16x8*)&smB[row * 64 + kk * 32 + fk];
            }
            #pragma unroll
            for (int m = 0; m < 4; m++)
                #pragma unroll
                for (int n = 0; n < 4; n++)
                    acc[m][n] = __builtin_amdgcn_mfma_f32_16x16x32_bf16(
                        af[m], bfr[n], acc[m][n], 0, 0, 0);
        }
        __syncthreads();
    }

    int crow0 = (lane >> 4) * 4;
    #pragma unroll
    for (int n = 0; n < 4; n++) {
        int col = n0 + wc * 64 + n * 16 + fr;
        float sc = scale[col], sh = shift[col];
        #pragma unroll
        for (int m = 0; m < 4; m++) {
            int rbase = m0 + wr * 64 + m * 16 + crow0;
            #pragma unroll
            for (int j = 0; j < 4; j++) {
                float v = acc[m][n][j] * sc + sh;
                v = v > 0.f ? v : 0.f;
                xout[(long)(rbase + j) * COUT + col] = f2bf(v);
            }
        }
    }
}

// --- K2: 1x1 conv (256->25) + bias + softmax -> kmaps [pix][25] ----------
__global__ __launch_bounds__(256) void conv2_softmax(
        const unsigned short* __restrict__ x, const float* __restrict__ w2,
        const float* __restrict__ b2, float* __restrict__ kmaps) {
    __shared__ float w2s[NORD * 256];
    __shared__ float b2s[NORD];
    for (int i = threadIdx.x; i < NORD * 256; i += 256) w2s[i] = w2[i];
    if (threadIdx.x < NORD) b2s[threadIdx.x] = b2[threadIdx.x];
    __syncthreads();
    long pix = (long)blockIdx.x * 256 + threadIdx.x;
    float acc[NORD];
    #pragma unroll
    for (int o = 0; o < NORD; o++) acc[o] = b2s[o];
    const unsigned short* xr = x + pix * COUT;
    for (int kc = 0; kc < 32; kc++) {
        uint4 raw = *(const uint4*)(xr + kc * 8);
        float xf[8];
        xf[0] = bf_lo(raw.x); xf[1] = bf_hi(raw.x);
        xf[2] = bf_lo(raw.y); xf[3] = bf_hi(raw.y);
        xf[4] = bf_lo(raw.z); xf[5] = bf_hi(raw.z);
        xf[6] = bf_lo(raw.w); xf[7] = bf_hi(raw.w);
        #pragma unroll
        for (int o = 0; o < NORD; o++) {
            const float* wrow = &w2s[o * 256 + kc * 8];
            float4 wa = *(const float4*)(wrow);
            float4 wb = *(const float4*)(wrow + 4);
            acc[o] += xf[0] * wa.x + xf[1] * wa.y + xf[2] * wa.z + xf[3] * wa.w
                    + xf[4] * wb.x + xf[5] * wb.y + xf[6] * wb.z + xf[7] * wb.w;
        }
    }
    float mx = acc[0];
    #pragma unroll
    for (int o = 1; o < NORD; o++) mx = fmaxf(mx, acc[o]);
    float s = 0.f;
    #pragma unroll
    for (int o = 0; o < NORD; o++) { acc[o] = expf(acc[o] - mx); s += acc[o]; }
    float inv = 1.f / s;
    float* kout = kmaps + pix * NORD;
    #pragma unroll
    for (int o = 0; o < NORD; o++) kout[o] = acc[o] * inv;
}

// --- K3: 25-tap weighted propagation -------------------------------------
__global__ __launch_bounds__(576) void propagate(
        const float* __restrict__ src, const float* __restrict__ kmaps,
        float* __restrict__ out) {
    __shared__ float sm[28 * 28];
    int b  = blockIdx.y;
    int cg = blockIdx.x;         // 16 channels per block
    int tid = threadIdx.x;       // pixel id 0..575
    int y = tid / 24, x = tid - y * 24;
    float km[NORD];
    const float* kp = kmaps + ((long)b * NPIX + tid) * NORD;
    #pragma unroll
    for (int o = 0; o < NORD; o++) km[o] = kp[o];
    for (int c = 0; c < 16; c++) {
        int cc = cg * 16 + c;
        const float* sp = src + ((long)b * CIN + cc) * NPIX;
        __syncthreads();
        for (int t = tid; t < 28 * 28; t += 576) {
            int yy = t / 28, xx = t - yy * 28;
            float v = 0.f;
            if (yy >= 2 && yy < 26 && xx >= 2 && xx < 26)
                v = sp[(yy - 2) * 24 + (xx - 2)];
            sm[t] = v;
        }
        __syncthreads();
        float a = 0.f;
        #pragma unroll
        for (int o = 0; o < NORD; o++) {
            int dy = o / 5 - 2, dx = o % 5 - 2;
            a += km[o] * sm[(y + 2 + dy) * 28 + (x + 2 + dx)];
        }
        out[((long)b * CIN + cc) * NPIX + tid] = a;
    }
}

extern "C" void kernel_launch(void* const* d_in, const int* in_sizes, int n_in,
                              void* d_out, int out_size, void* d_ws, size_t ws_size,
                              hipStream_t stream) {
    const float* src = (const float*)d_in[0];
    const float* det = (const float*)d_in[1];
    const float* w1  = (const float*)d_in[2];
    const float* b1  = (const float*)d_in[3];
    const float* gam = (const float*)d_in[4];
    const float* bet = (const float*)d_in[5];
    const float* mu  = (const float*)d_in[6];
    const float* var = (const float*)d_in[7];
    const float* w2  = (const float*)d_in[8];
    const float* b2  = (const float*)d_in[9];
    float* out = (float*)d_out;

    char* ws = (char*)d_ws;
    size_t off = 0;
    unsigned short* apad = (unsigned short*)(ws + off); off += (size_t)BATCH * HP * WP * CCAT * 2;   // 88,604,672
    unsigned short* bt   = (unsigned short*)(ws + off); off += (size_t)COUT * KDIM * 2;              //  2,359,296
    unsigned short* xbuf = (unsigned short*)(ws + off); off += (size_t)MDIM * COUT * 2;              // 37,748,736
    float* kmaps = (float*)(ws + off); off += (size_t)MDIM * NORD * 4;                               //  7,372,800
    float* scale = (float*)(ws + off); off += 1024;
    float* shift = (float*)(ws + off); off += 1024;

    zero_halo<<<3200, 256, 0, stream>>>(apad);
    prep_transpose<<<dim3(3, 8, BATCH), 256, 0, stream>>>(src, det, apad);
    prep_w<<<4608, 256, 0, stream>>>(w1, b1, gam, bet, mu, var, bt, scale, shift);
    conv1_gemm<<<1152, 256, 0, stream>>>(apad, bt, scale, shift, xbuf);
    conv2_softmax<<<288, 256, 0, stream>>>(xbuf, w2, b2, kmaps);
    propagate<<<dim3(16, BATCH), 576, 0, stream>>>(src, kmaps, out);
}

// Round 3
// 417.712 us; speedup vs baseline: 1.9734x; 1.1799x over previous
//
#include <hip/hip_runtime.h>
#include <hip/hip_bf16.h>
#include <stdint.h>

#define BATCH 128
#define CIN   256
#define CCAT  512
#define HH    24
#define WW    24
#define HP    26
#define WP    26
#define COUT  256
#define KDIM  4608   // 9*512
#define NPIX  576    // 24*24
#define MDIM  73728  // 128*576
#define NORD  25

typedef __attribute__((ext_vector_type(8))) short bf16x8;
typedef __attribute__((ext_vector_type(4))) float f32x4;

__device__ __forceinline__ unsigned short f2bf(float v) {
    union { float f; unsigned u; } x; x.f = v;
    unsigned r = x.u + 0x7fffu + ((x.u >> 16) & 1u);
    return (unsigned short)(r >> 16);
}
__device__ __forceinline__ float bf_lo(unsigned w) {
    union { unsigned u; float f; } x; x.u = w << 16; return x.f;
}
__device__ __forceinline__ float bf_hi(unsigned w) {
    union { unsigned u; float f; } x; x.u = w & 0xffff0000u; return x.f;
}

__device__ __forceinline__ void async_copy16(const void* gsrc, void* ldst) {
    __builtin_amdgcn_global_load_lds(
        (const __attribute__((address_space(1))) unsigned int*)gsrc,
        (__attribute__((address_space(3))) unsigned int*)ldst, 16, 0, 0);
}

// --- K0a: coalesced NCHW fp32 -> padded NHWC bf16 via LDS transpose ------
#define PTILE 192
#define LSTR  72
__global__ __launch_bounds__(256) void prep_transpose(
        const float* __restrict__ src, const float* __restrict__ det,
        unsigned short* __restrict__ apad) {
    __shared__ unsigned short lds[PTILE * LSTR];
    int pt = blockIdx.x;
    int cg = blockIdx.y;
    int b  = blockIdx.z;
    int c0 = cg * 64;
    int p0 = pt * PTILE;
    const float* inp = (c0 < CIN)
        ? (src + ((long)b * CIN + c0) * NPIX)
        : (det + ((long)b * CIN + (c0 - CIN)) * NPIX);
    int tid = threadIdx.x;

    #pragma unroll
    for (int it = 0; it < 12; it++) {
        int l  = it * 256 + tid;
        int cq = l / PTILE;
        int px = l - cq * PTILE;
        const float* pb = inp + (long)cq * 4 * NPIX + p0 + px;
        unsigned short v0 = f2bf(pb[0 * NPIX]);
        unsigned short v1 = f2bf(pb[1 * NPIX]);
        unsigned short v2 = f2bf(pb[2 * NPIX]);
        unsigned short v3 = f2bf(pb[3 * NPIX]);
        uint2 w;
        w.x = (unsigned)v0 | ((unsigned)v1 << 16);
        w.y = (unsigned)v2 | ((unsigned)v3 << 16);
        *(uint2*)&lds[px * LSTR + cq * 4] = w;
    }
    __syncthreads();

    #pragma unroll
    for (int it = 0; it < 6; it++) {
        int l   = it * 256 + tid;
        int px  = l >> 3;
        int ch8 = l & 7;
        uint4 w = *(const uint4*)&lds[px * LSTR + ch8 * 8];
        int p  = p0 + px;
        int y  = p / WW, x = p - y * WW;
        long o = (((long)b * HP + (y + 1)) * WP + (x + 1)) * CCAT + c0 + ch8 * 8;
        *(uint4*)(apad + o) = w;
    }
}

// --- K0a': zero the 1-wide halo ------------------------------------------
__global__ __launch_bounds__(256) void zero_halo(unsigned short* __restrict__ apad) {
    int t = blockIdx.x * 256 + threadIdx.x;
    int ch8 = t & 63;
    int r   = t >> 6;
    int hp  = r % 100;
    int b   = r / 100;
    int y, x;
    if (hp < 26)      { y = 0;       x = hp; }
    else if (hp < 52) { y = 25;      x = hp - 26; }
    else if (hp < 76) { y = hp - 51; x = 0; }
    else              { y = hp - 75; x = 25; }
    long o = (((long)b * HP + y) * WP + x) * CCAT + ch8 * 8;
    *(uint4*)(apad + o) = (uint4){0u, 0u, 0u, 0u};
}

// --- K0b: w1 OIHW -> B^T [256][4608] bf16; fold BN+bias ------------------
__global__ __launch_bounds__(256) void prep_w(
        const float* __restrict__ w1, const float* __restrict__ b1,
        const float* __restrict__ gam, const float* __restrict__ bet,
        const float* __restrict__ mu, const float* __restrict__ var,
        unsigned short* __restrict__ bt,
        float* __restrict__ scale, float* __restrict__ shift) {
    int idx = blockIdx.x * 256 + threadIdx.x;
    if (idx < COUT * KDIM) {
        int n = idx / KDIM;
        int k = idx - n * KDIM;
        int s = k >> 9;
        int ci = k & 511;
        int ky = s / 3, kx = s - ky * 3;
        float v = w1[(((long)n * 512 + ci) * 3 + ky) * 3 + kx];
        bt[idx] = f2bf(v);
    }
    if (blockIdx.x == 0 && threadIdx.x < COUT) {
        int c = threadIdx.x;
        float inv = gam[c] * rsqrtf(var[c] + 1e-5f);
        scale[c] = inv;
        shift[c] = (b1[c] - mu[c]) * inv + bet[c];
    }
}

// --- K1: conv1 implicit GEMM, 256x256 tile, 8-wave, 4-phase counted-vmcnt
// C[73728][256] = A_im2col[73728][4608] x B^T[256][4608]
// LDS: 2 buf x (A 256x64 + B 256x64) bf16 = 128 KiB. T2 swizzle via
// pre-swizzled global source (linear gload_lds dest) + XOR'd ds_read.
#define STAGE_A(j, nb, soff) \
    async_copy16(apad + aSrc[j] + (soff), (void*)&lds[(nb)*32768 + (j)*4096 + w*512])
#define STAGE_B(j, nb, koff) \
    async_copy16(bt + bSrc[j] + (koff), (void*)&lds[(nb)*32768 + 16384 + (j)*4096 + w*512])
#define BAR()  __builtin_amdgcn_s_barrier()
#define WAITV2() { asm volatile("s_waitcnt vmcnt(2)" ::: "memory"); }
#define WAITV0() { asm volatile("s_waitcnt vmcnt(0)" ::: "memory"); }
#define WAITL()  { asm volatile("s_waitcnt lgkmcnt(0)" ::: "memory"); __builtin_amdgcn_sched_barrier(0); }

__global__ __launch_bounds__(512, 2) void conv1_gemm(
        const unsigned short* __restrict__ apad,
        const unsigned short* __restrict__ bt,
        const float* __restrict__ scale, const float* __restrict__ shift,
        unsigned short* __restrict__ xout) {
    __shared__ unsigned short lds[65536];   // 128 KiB
    const int tid  = threadIdx.x;
    const int w    = tid >> 6;
    const int lane = tid & 63;
    const int wr = w >> 2, wc = w & 3;      // 2M x 4N wave grid
    const int fr = lane & 15, ls = lane >> 4;
    const long m0 = (long)blockIdx.x * 256;

    // staging sources: instr j covers tile rows j*64..j*64+63, 8 thr/row,
    // 16B/thr; logical slot pre-swizzled so linear LDS fill lands swizzled
    const int rowq = tid >> 3;                  // 0..63
    const int sl   = (tid & 7) ^ (rowq & 7);    // swizzled 16B slot
    long aSrc[4], bSrc[4];
    #pragma unroll
    for (int j = 0; j < 4; j++) {
        int r = j * 64 + rowq;
        long m = m0 + r;
        int b  = (int)(m / NPIX);
        int rr = (int)(m - (long)b * NPIX);
        int y = rr / WW, x = rr - y * WW;
        aSrc[j] = (((long)b * HP + y) * WP + x) * (long)CCAT + sl * 8;
        bSrc[j] = (long)r * KDIM + sl * 8;
    }

    // fragment read offsets (bytes): row*128 + ((kk*4+ls)^(fr&7))*16
    const int rb   = fr & 7;
    const int csw0 = ((ls    ) ^ rb) << 4;
    const int csw1 = ((ls + 4) ^ rb) << 4;
    const int aBase = (wr * 128 + fr) * 128;          // + mh*8192 + m*2048
    const int bBase = 32768 + (wc * 64 + fr) * 128;   // + n*2048

    f32x4 acc[8][4];
    #pragma unroll
    for (int i = 0; i < 8; i++)
        #pragma unroll
        for (int j = 0; j < 4; j++) acc[i][j] = (f32x4){0.f, 0.f, 0.f, 0.f};

    // prologue: stage tile 0 into buf 0 (order B0..B3,A0,A2,A1,A3)
    STAGE_B(0, 0, 0); STAGE_B(1, 0, 0); STAGE_B(2, 0, 0); STAGE_B(3, 0, 0);
    STAGE_A(0, 0, 0); STAGE_A(2, 0, 0); STAGE_A(1, 0, 0); STAGE_A(3, 0, 0);
    WAITV2();
    BAR();

    bf16x8 afr[4], bfr[4];
    int nb = 0;
    for (int kt = 0; kt < 71; kt++) {
        const int ktn = kt + 1;
        const int seg = ktn >> 3;
        const int ky = seg / 3, kx = seg - ky * 3;
        const long soff = (long)(ky * WP + kx) * CCAT + (ktn & 7) * 64;
        const long koff = (long)ktn * 64;
        const int pb = nb ^ 1;
        const char* L = (const char*)lds + nb * 65536;

        // ---- p0: kk=0, mh=0 ----
        #pragma unroll
        for (int n = 0; n < 4; n++)
            bfr[n] = *(const bf16x8*)(L + bBase + n * 2048 + csw0);
        #pragma unroll
        for (int m = 0; m < 4; m++)
            afr[m] = *(const bf16x8*)(L + aBase + m * 2048 + csw0);
        STAGE_B(0, pb, koff); STAGE_B(1, pb, koff);
        WAITV2();
        BAR(); WAITL();
        __builtin_amdgcn_s_setprio(1);
        #pragma unroll
        for (int m = 0; m < 4; m++)
            #pragma unroll
            for (int n = 0; n < 4; n++)
                acc[m][n] = __builtin_amdgcn_mfma_f32_16x16x32_bf16(afr[m], bfr[n], acc[m][n], 0, 0, 0);
        __builtin_amdgcn_s_setprio(0);
        BAR();

        // ---- p1: kk=0, mh=1 ----
        #pragma unroll
        for (int m = 0; m < 4; m++)
            afr[m] = *(const bf16x8*)(L + aBase + 8192 + m * 2048 + csw0);
        STAGE_B(2, pb, koff); STAGE_B(3, pb, koff);
        BAR(); WAITL();
        __builtin_amdgcn_s_setprio(1);
        #pragma unroll
        for (int m = 0; m < 4; m++)
            #pragma unroll
            for (int n = 0; n < 4; n++)
                acc[4 + m][n] = __builtin_amdgcn_mfma_f32_16x16x32_bf16(afr[m], bfr[n], acc[4 + m][n], 0, 0, 0);
        __builtin_amdgcn_s_setprio(0);
        BAR();

        // ---- p2: kk=1, mh=0 ----
        #pragma unroll
        for (int n = 0; n < 4; n++)
            bfr[n] = *(const bf16x8*)(L + bBase + n * 2048 + csw1);
        #pragma unroll
        for (int m = 0; m < 4; m++)
            afr[m] = *(const bf16x8*)(L + aBase + m * 2048 + csw1);
        STAGE_A(0, pb, soff); STAGE_A(2, pb, soff);
        BAR(); WAITL();
        __builtin_amdgcn_s_setprio(1);
        #pragma unroll
        for (int m = 0; m < 4; m++)
            #pragma unroll
            for (int n = 0; n < 4; n++)
                acc[m][n] = __builtin_amdgcn_mfma_f32_16x16x32_bf16(afr[m], bfr[n], acc[m][n], 0, 0, 0);
        __builtin_amdgcn_s_setprio(0);
        BAR();

        // ---- p3: kk=1, mh=1 ----
        #pragma unroll
        for (int m = 0; m < 4; m++)
            afr[m] = *(const bf16x8*)(L + aBase + 8192 + m * 2048 + csw1);
        STAGE_A(1, pb, soff); STAGE_A(3, pb, soff);
        WAITV2();
        BAR(); WAITL();
        __builtin_amdgcn_s_setprio(1);
        #pragma unroll
        for (int m = 0; m < 4; m++)
            #pragma unroll
            for (int n = 0; n < 4; n++)
                acc[4 + m][n] = __builtin_amdgcn_mfma_f32_16x16x32_bf16(afr[m], bfr[n], acc[4 + m][n], 0, 0, 0);
        __builtin_amdgcn_s_setprio(0);
        BAR();

        nb ^= 1;
    }

    // ---- peeled last tile (kt=71), no staging ----
    {
        const char* L = (const char*)lds + nb * 65536;
        // p0
        #pragma unroll
        for (int n = 0; n < 4; n++)
            bfr[n] = *(const bf16x8*)(L + bBase + n * 2048 + csw0);
        #pragma unroll
        for (int m = 0; m < 4; m++)
            afr[m] = *(const bf16x8*)(L + aBase + m * 2048 + csw0);
        WAITV0();
        BAR(); WAITL();
        #pragma unroll
        for (int m = 0; m < 4; m++)
            #pragma unroll
            for (int n = 0; n < 4; n++)
                acc[m][n] = __builtin_amdgcn_mfma_f32_16x16x32_bf16(afr[m], bfr[n], acc[m][n], 0, 0, 0);
        BAR();
        // p1
        #pragma unroll
        for (int m = 0; m < 4; m++)
            afr[m] = *(const bf16x8*)(L + aBase + 8192 + m * 2048 + csw0);
        WAITL();
        #pragma unroll
        for (int m = 0; m < 4; m++)
            #pragma unroll
            for (int n = 0; n < 4; n++)
                acc[4 + m][n] = __builtin_amdgcn_mfma_f32_16x16x32_bf16(afr[m], bfr[n], acc[4 + m][n], 0, 0, 0);
        // p2
        #pragma unroll
        for (int n = 0; n < 4; n++)
            bfr[n] = *(const bf16x8*)(L + bBase + n * 2048 + csw1);
        #pragma unroll
        for (int m = 0; m < 4; m++)
            afr[m] = *(const bf16x8*)(L + aBase + m * 2048 + csw1);
        WAITL();
        #pragma unroll
        for (int m = 0; m < 4; m++)
            #pragma unroll
            for (int n = 0; n < 4; n++)
                acc[m][n] = __builtin_amdgcn_mfma_f32_16x16x32_bf16(afr[m], bfr[n], acc[m][n], 0, 0, 0);
        // p3
        #pragma unroll
        for (int m = 0; m < 4; m++)
            afr[m] = *(const bf16x8*)(L + aBase + 8192 + m * 2048 + csw1);
        WAITL();
        #pragma unroll
        for (int m = 0; m < 4; m++)
            #pragma unroll
            for (int n = 0; n < 4; n++)
                acc[4 + m][n] = __builtin_amdgcn_mfma_f32_16x16x32_bf16(afr[m], bfr[n], acc[4 + m][n], 0, 0, 0);
    }

    // ---- epilogue: BN+ReLU fused, bf16 store ----
    #pragma unroll
    for (int n = 0; n < 4; n++) {
        int col = wc * 64 + n * 16 + fr;
        float sc = scale[col], sh = shift[col];
        #pragma unroll
        for (int m = 0; m < 8; m++) {
            long rbase = m0 + wr * 128 + m * 16 + ls * 4;
            #pragma unroll
            for (int j = 0; j < 4; j++) {
                float v = acc[m][n][j] * sc + sh;
                v = v > 0.f ? v : 0.f;
                xout[(rbase + j) * COUT + col] = f2bf(v);
            }
        }
    }
}

// --- K2: 1x1 conv (256->25) + bias + softmax -> kmaps [pix][25] ----------
__global__ __launch_bounds__(256) void conv2_softmax(
        const unsigned short* __restrict__ x, const float* __restrict__ w2,
        const float* __restrict__ b2, float* __restrict__ kmaps) {
    __shared__ float w2s[NORD * 256];
    __shared__ float b2s[NORD];
    for (int i = threadIdx.x; i < NORD * 256; i += 256) w2s[i] = w2[i];
    if (threadIdx.x < NORD) b2s[threadIdx.x] = b2[threadIdx.x];
    __syncthreads();
    long pix = (long)blockIdx.x * 256 + threadIdx.x;
    float acc[NORD];
    #pragma unroll
    for (int o = 0; o < NORD; o++) acc[o] = b2s[o];
    const unsigned short* xr = x + pix * COUT;
    for (int kc = 0; kc < 32; kc++) {
        uint4 raw = *(const uint4*)(xr + kc * 8);
        float xf[8];
        xf[0] = bf_lo(raw.x); xf[1] = bf_hi(raw.x);
        xf[2] = bf_lo(raw.y); xf[3] = bf_hi(raw.y);
        xf[4] = bf_lo(raw.z); xf[5] = bf_hi(raw.z);
        xf[6] = bf_lo(raw.w); xf[7] = bf_hi(raw.w);
        #pragma unroll
        for (int o = 0; o < NORD; o++) {
            const float* wrow = &w2s[o * 256 + kc * 8];
            float4 wa = *(const float4*)(wrow);
            float4 wb = *(const float4*)(wrow + 4);
            acc[o] += xf[0] * wa.x + xf[1] * wa.y + xf[2] * wa.z + xf[3] * wa.w
                    + xf[4] * wb.x + xf[5] * wb.y + xf[6] * wb.z + xf[7] * wb.w;
        }
    }
    float mx = acc[0];
    #pragma unroll
    for (int o = 1; o < NORD; o++) mx = fmaxf(mx, acc[o]);
    float s = 0.f;
    #pragma unroll
    for (int o = 0; o < NORD; o++) { acc[o] = expf(acc[o] - mx); s += acc[o]; }
    float inv = 1.f / s;
    float* kout = kmaps + pix * NORD;
    #pragma unroll
    for (int o = 0; o < NORD; o++) kout[o] = acc[o] * inv;
}

// --- K3: 25-tap weighted propagation -------------------------------------
__global__ __launch_bounds__(576) void propagate(
        const float* __restrict__ src, const float* __restrict__ kmaps,
        float* __restrict__ out) {
    __shared__ float sm[28 * 28];
    int b  = blockIdx.y;
    int cg = blockIdx.x;
    int tid = threadIdx.x;
    int y = tid / 24, x = tid - y * 24;
    float km[NORD];
    const float* kp = kmaps + ((long)b * NPIX + tid) * NORD;
    #pragma unroll
    for (int o = 0; o < NORD; o++) km[o] = kp[o];
    for (int c = 0; c < 16; c++) {
        int cc = cg * 16 + c;
        const float* sp = src + ((long)b * CIN + cc) * NPIX;
        __syncthreads();
        for (int t = tid; t < 28 * 28; t += 576) {
            int yy = t / 28, xx = t - yy * 28;
            float v = 0.f;
            if (yy >= 2 && yy < 26 && xx >= 2 && xx < 26)
                v = sp[(yy - 2) * 24 + (xx - 2)];
            sm[t] = v;
        }
        __syncthreads();
        float a = 0.f;
        #pragma unroll
        for (int o = 0; o < NORD; o++) {
            int dy = o / 5 - 2, dx = o % 5 - 2;
            a += km[o] * sm[(y + 2 + dy) * 28 + (x + 2 + dx)];
        }
        out[((long)b * CIN + cc) * NPIX + tid] = a;
    }
}

extern "C" void kernel_launch(void* const* d_in, const int* in_sizes, int n_in,
                              void* d_out, int out_size, void* d_ws, size_t ws_size,
                              hipStream_t stream) {
    const float* src = (const float*)d_in[0];
    const float* det = (const float*)d_in[1];
    const float* w1  = (const float*)d_in[2];
    const float* b1  = (const float*)d_in[3];
    const float* gam = (const float*)d_in[4];
    const float* bet = (const float*)d_in[5];
    const float* mu  = (const float*)d_in[6];
    const float* var = (const float*)d_in[7];
    const float* w2  = (const float*)d_in[8];
    const float* b2  = (const float*)d_in[9];
    float* out = (float*)d_out;

    char* ws = (char*)d_ws;
    size_t off = 0;
    unsigned short* apad = (unsigned short*)(ws + off); off += (size_t)BATCH * HP * WP * CCAT * 2;
    unsigned short* bt   = (unsigned short*)(ws + off); off += (size_t)COUT * KDIM * 2;
    unsigned short* xbuf = (unsigned short*)(ws + off); off += (size_t)MDIM * COUT * 2;
    float* kmaps = (float*)(ws + off); off += (size_t)MDIM * NORD * 4;
    float* scale = (float*)(ws + off); off += 1024;
    float* shift = (float*)(ws + off); off += 1024;

    zero_halo<<<3200, 256, 0, stream>>>(apad);
    prep_transpose<<<dim3(3, 8, BATCH), 256, 0, stream>>>(src, det, apad);
    prep_w<<<4608, 256, 0, stream>>>(w1, b1, gam, bet, mu, var, bt, scale, shift);
    conv1_gemm<<<288, 512, 0, stream>>>(apad, bt, scale, shift, xbuf);
    conv2_softmax<<<288, 256, 0, stream>>>(xbuf, w2, b2, kmaps);
    propagate<<<dim3(16, BATCH), 576, 0, stream>>>(src, kmaps, out);
}

// Round 4
// 358.728 us; speedup vs baseline: 2.2979x; 1.1644x over previous
//
#include <hip/hip_runtime.h>
#include <hip/hip_bf16.h>
#include <stdint.h>

#define BATCH 128
#define CIN   256
#define CCAT  512
#define HH    24
#define WW    24
#define HP    26
#define WP    26
#define COUT  256
#define KDIM  4608   // 9*512
#define NPIX  576    // 24*24
#define MDIM  73728  // 128*576
#define NORD  25

typedef __attribute__((ext_vector_type(8))) short bf16x8;
typedef __attribute__((ext_vector_type(4))) float f32x4;

__device__ __forceinline__ unsigned short f2bf(float v) {
    union { float f; unsigned u; } x; x.f = v;
    unsigned r = x.u + 0x7fffu + ((x.u >> 16) & 1u);
    return (unsigned short)(r >> 16);
}
__device__ __forceinline__ float bf_lo(unsigned w) {
    union { unsigned u; float f; } x; x.u = w << 16; return x.f;
}
__device__ __forceinline__ float bf_hi(unsigned w) {
    union { unsigned u; float f; } x; x.u = w & 0xffff0000u; return x.f;
}

__device__ __forceinline__ void async_copy16(const void* gsrc, void* ldst) {
    __builtin_amdgcn_global_load_lds(
        (const __attribute__((address_space(1))) unsigned int*)gsrc,
        (__attribute__((address_space(3))) unsigned int*)ldst, 16, 0, 0);
}

// --- K0a: coalesced NCHW fp32 -> padded NHWC bf16 via LDS transpose ------
#define PTILE 192
#define LSTR  72
__global__ __launch_bounds__(256) void prep_transpose(
        const float* __restrict__ src, const float* __restrict__ det,
        unsigned short* __restrict__ apad) {
    __shared__ unsigned short lds[PTILE * LSTR];
    int pt = blockIdx.x;
    int cg = blockIdx.y;
    int b  = blockIdx.z;
    int c0 = cg * 64;
    int p0 = pt * PTILE;
    const float* inp = (c0 < CIN)
        ? (src + ((long)b * CIN + c0) * NPIX)
        : (det + ((long)b * CIN + (c0 - CIN)) * NPIX);
    int tid = threadIdx.x;

    #pragma unroll
    for (int it = 0; it < 12; it++) {
        int l  = it * 256 + tid;
        int cq = l / PTILE;
        int px = l - cq * PTILE;
        const float* pb = inp + (long)cq * 4 * NPIX + p0 + px;
        unsigned short v0 = f2bf(pb[0 * NPIX]);
        unsigned short v1 = f2bf(pb[1 * NPIX]);
        unsigned short v2 = f2bf(pb[2 * NPIX]);
        unsigned short v3 = f2bf(pb[3 * NPIX]);
        uint2 w;
        w.x = (unsigned)v0 | ((unsigned)v1 << 16);
        w.y = (unsigned)v2 | ((unsigned)v3 << 16);
        *(uint2*)&lds[px * LSTR + cq * 4] = w;
    }
    __syncthreads();

    #pragma unroll
    for (int it = 0; it < 6; it++) {
        int l   = it * 256 + tid;
        int px  = l >> 3;
        int ch8 = l & 7;
        uint4 w = *(const uint4*)&lds[px * LSTR + ch8 * 8];
        int p  = p0 + px;
        int y  = p / WW, x = p - y * WW;
        long o = (((long)b * HP + (y + 1)) * WP + (x + 1)) * CCAT + c0 + ch8 * 8;
        *(uint4*)(apad + o) = w;
    }
}

// --- K0a': zero the 1-wide halo ------------------------------------------
__global__ __launch_bounds__(256) void zero_halo(unsigned short* __restrict__ apad) {
    int t = blockIdx.x * 256 + threadIdx.x;
    int ch8 = t & 63;
    int r   = t >> 6;
    int hp  = r % 100;
    int b   = r / 100;
    int y, x;
    if (hp < 26)      { y = 0;       x = hp; }
    else if (hp < 52) { y = 25;      x = hp - 26; }
    else if (hp < 76) { y = hp - 51; x = 0; }
    else              { y = hp - 75; x = 25; }
    long o = (((long)b * HP + y) * WP + x) * CCAT + ch8 * 8;
    *(uint4*)(apad + o) = (uint4){0u, 0u, 0u, 0u};
}

// --- K0b: w1 OIHW -> B^T [256][4608] bf16; fold BN+bias ------------------
__global__ __launch_bounds__(256) void prep_w(
        const float* __restrict__ w1, const float* __restrict__ b1,
        const float* __restrict__ gam, const float* __restrict__ bet,
        const float* __restrict__ mu, const float* __restrict__ var,
        unsigned short* __restrict__ bt,
        float* __restrict__ scale, float* __restrict__ shift) {
    int idx = blockIdx.x * 256 + threadIdx.x;
    if (idx < COUT * KDIM) {
        int n = idx / KDIM;
        int k = idx - n * KDIM;
        int s = k >> 9;
        int ci = k & 511;
        int ky = s / 3, kx = s - ky * 3;
        float v = w1[(((long)n * 512 + ci) * 3 + ky) * 3 + kx];
        bt[idx] = f2bf(v);
    }
    if (blockIdx.x == 0 && threadIdx.x < COUT) {
        int c = threadIdx.x;
        float inv = gam[c] * rsqrtf(var[c] + 1e-5f);
        scale[c] = inv;
        shift[c] = (b1[c] - mu[c]) * inv + bet[c];
    }
}

// --- K1: conv1 implicit GEMM, 192x128 tile, 8-wave, 4-phase counted-vmcnt
// grid = 384 x 2 = 768 blocks = exactly 3/CU; LDS 80 KiB = 2 blocks/CU.
// C[73728][256] = A_im2col[73728][4608] x B^T[256][4608]
#define ABUF_SH 12288   // 192*64 shorts
#define BUF_SH  20480   // (192+128)*64 shorts per buffer
#define STAGE_A(j, nb, soff) \
    async_copy16(apad + aSrc[j] + (soff), (void*)&lds[(nb)*BUF_SH + (j)*4096 + w*512])
#define STAGE_B(j, nb, koff) \
    async_copy16(bt + bSrc[j] + (koff), (void*)&lds[(nb)*BUF_SH + ABUF_SH + (j)*4096 + w*512])
#define BAR()  __builtin_amdgcn_s_barrier()
#define WAITV2() { asm volatile("s_waitcnt vmcnt(2)" ::: "memory"); }
#define WAITV0() { asm volatile("s_waitcnt vmcnt(0)" ::: "memory"); }
#define WAITL()  { asm volatile("s_waitcnt lgkmcnt(0)" ::: "memory"); __builtin_amdgcn_sched_barrier(0); }

__global__ __launch_bounds__(512, 2) void conv1_gemm(
        const unsigned short* __restrict__ apad,
        const unsigned short* __restrict__ bt,
        const float* __restrict__ scale, const float* __restrict__ shift,
        unsigned short* __restrict__ xout) {
    __shared__ unsigned short lds[40960];   // 80 KiB, 2 buffers
    const int tid  = threadIdx.x;
    const int w    = tid >> 6;
    const int lane = tid & 63;
    const int wr = w >> 2, wc = w & 3;      // 2M x 4N wave grid (96x32/wave)
    const int fr = lane & 15, ls = lane >> 4;

    // XCD-aware bijective swizzle (768 % 8 == 0)
    const int Lb = blockIdx.x;
    const int logical = (Lb & 7) * 96 + (Lb >> 3);
    const int n0 = (logical & 1) * 128;
    const long m0 = (long)(logical >> 1) * 192;

    // staging sources: A instr j covers rows j*64..j*64+63 (j=0..2),
    // B instr j covers rows j*64.. (j=0..1); 8 thr/row, 16B/thr,
    // slot pre-swizzled so linear gload_lds fill lands swizzled.
    const int rowq = tid >> 3;                  // 0..63
    const int sl   = (tid & 7) ^ (rowq & 7);    // swizzled 16B slot
    long aSrc[3], bSrc[2];
    #pragma unroll
    for (int j = 0; j < 3; j++) {
        int r = j * 64 + rowq;
        long m = m0 + r;
        int b  = (int)(m / NPIX);
        int rr = (int)(m - (long)b * NPIX);
        int y = rr / WW, x = rr - y * WW;
        aSrc[j] = (((long)b * HP + y) * WP + x) * (long)CCAT + sl * 8;
    }
    #pragma unroll
    for (int j = 0; j < 2; j++)
        bSrc[j] = (long)(n0 + j * 64 + rowq) * KDIM + sl * 8;

    // fragment read offsets (bytes): row*128 + ((kk*4+ls)^(fr&7))*16
    const int rb   = fr & 7;
    const int csw0 = ((ls    ) ^ rb) << 4;
    const int csw1 = ((ls + 4) ^ rb) << 4;
    const int aBase = (wr * 96 + fr) * 128;          // + m*2048, m=0..5
    const int bBase = 24576 + (wc * 32 + fr) * 128;  // + n*2048, n=0..1

    f32x4 acc[6][2];
    #pragma unroll
    for (int i = 0; i < 6; i++)
        #pragma unroll
        for (int j = 0; j < 2; j++) acc[i][j] = (f32x4){0.f, 0.f, 0.f, 0.f};

    // prologue: stage tile 0 into buf 0 (5 loads in flight)
    STAGE_B(0, 0, 0); STAGE_B(1, 0, 0);
    STAGE_A(0, 0, 0); STAGE_A(1, 0, 0); STAGE_A(2, 0, 0);

    bf16x8 afr[3], bfr[2];
    int nb = 0;
    for (int kt = 0; kt < 71; kt++) {
        const int ktn = kt + 1;
        const int seg = ktn >> 3;
        const int ky = seg / 3, kx = seg - ky * 3;
        const long soff = (long)(ky * WP + kx) * CCAT + (ktn & 7) * 64;
        const long koff = (long)ktn * 64;
        const int pb = nb ^ 1;
        const char* L = (const char*)lds + nb * (BUF_SH * 2);

        // ---- p0: kk=0, mh=0 ----
        STAGE_B(0, pb, koff); STAGE_B(1, pb, koff);
        WAITV2();            // current tile's 5 loads complete; 2 in flight
        BAR();
        #pragma unroll
        for (int n = 0; n < 2; n++)
            bfr[n] = *(const bf16x8*)(L + bBase + n * 2048 + csw0);
        #pragma unroll
        for (int m = 0; m < 3; m++)
            afr[m] = *(const bf16x8*)(L + aBase + m * 2048 + csw0);
        WAITL();
        __builtin_amdgcn_s_setprio(1);
        #pragma unroll
        for (int m = 0; m < 3; m++)
            #pragma unroll
            for (int n = 0; n < 2; n++)
                acc[m][n] = __builtin_amdgcn_mfma_f32_16x16x32_bf16(afr[m], bfr[n], acc[m][n], 0, 0, 0);
        __builtin_amdgcn_s_setprio(0);
        BAR();

        // ---- p1: kk=0, mh=1 ----
        #pragma unroll
        for (int m = 0; m < 3; m++)
            afr[m] = *(const bf16x8*)(L + aBase + (3 + m) * 2048 + csw0);
        STAGE_A(0, pb, soff); STAGE_A(1, pb, soff); STAGE_A(2, pb, soff);
        WAITL();
        __builtin_amdgcn_s_setprio(1);
        #pragma unroll
        for (int m = 0; m < 3; m++)
            #pragma unroll
            for (int n = 0; n < 2; n++)
                acc[3 + m][n] = __builtin_amdgcn_mfma_f32_16x16x32_bf16(afr[m], bfr[n], acc[3 + m][n], 0, 0, 0);
        __builtin_amdgcn_s_setprio(0);
        BAR();

        // ---- p2: kk=1, mh=0 ----
        #pragma unroll
        for (int n = 0; n < 2; n++)
            bfr[n] = *(const bf16x8*)(L + bBase + n * 2048 + csw1);
        #pragma unroll
        for (int m = 0; m < 3; m++)
            afr[m] = *(const bf16x8*)(L + aBase + m * 2048 + csw1);
        WAITL();
        __builtin_amdgcn_s_setprio(1);
        #pragma unroll
        for (int m = 0; m < 3; m++)
            #pragma unroll
            for (int n = 0; n < 2; n++)
                acc[m][n] = __builtin_amdgcn_mfma_f32_16x16x32_bf16(afr[m], bfr[n], acc[m][n], 0, 0, 0);
        __builtin_amdgcn_s_setprio(0);
        BAR();

        // ---- p3: kk=1, mh=1 ----
        #pragma unroll
        for (int m = 0; m < 3; m++)
            afr[m] = *(const bf16x8*)(L + aBase + (3 + m) * 2048 + csw1);
        WAITL();
        __builtin_amdgcn_s_setprio(1);
        #pragma unroll
        for (int m = 0; m < 3; m++)
            #pragma unroll
            for (int n = 0; n < 2; n++)
                acc[3 + m][n] = __builtin_amdgcn_mfma_f32_16x16x32_bf16(afr[m], bfr[n], acc[3 + m][n], 0, 0, 0);
        __builtin_amdgcn_s_setprio(0);
        BAR();

        nb ^= 1;
    }

    // ---- peeled last tile (kt=71), no prefetch ----
    {
        const char* L = (const char*)lds + nb * (BUF_SH * 2);
        WAITV0();
        BAR();
        // kk0 mh0
        #pragma unroll
        for (int n = 0; n < 2; n++)
            bfr[n] = *(const bf16x8*)(L + bBase + n * 2048 + csw0);
        #pragma unroll
        for (int m = 0; m < 3; m++)
            afr[m] = *(const bf16x8*)(L + aBase + m * 2048 + csw0);
        WAITL();
        #pragma unroll
        for (int m = 0; m < 3; m++)
            #pragma unroll
            for (int n = 0; n < 2; n++)
                acc[m][n] = __builtin_amdgcn_mfma_f32_16x16x32_bf16(afr[m], bfr[n], acc[m][n], 0, 0, 0);
        // kk0 mh1
        #pragma unroll
        for (int m = 0; m < 3; m++)
            afr[m] = *(const bf16x8*)(L + aBase + (3 + m) * 2048 + csw0);
        WAITL();
        #pragma unroll
        for (int m = 0; m < 3; m++)
            #pragma unroll
            for (int n = 0; n < 2; n++)
                acc[3 + m][n] = __builtin_amdgcn_mfma_f32_16x16x32_bf16(afr[m], bfr[n], acc[3 + m][n], 0, 0, 0);
        // kk1 mh0
        #pragma unroll
        for (int n = 0; n < 2; n++)
            bfr[n] = *(const bf16x8*)(L + bBase + n * 2048 + csw1);
        #pragma unroll
        for (int m = 0; m < 3; m++)
            afr[m] = *(const bf16x8*)(L + aBase + m * 2048 + csw1);
        WAITL();
        #pragma unroll
        for (int m = 0; m < 3; m++)
            #pragma unroll
            for (int n = 0; n < 2; n++)
                acc[m][n] = __builtin_amdgcn_mfma_f32_16x16x32_bf16(afr[m], bfr[n], acc[m][n], 0, 0, 0);
        // kk1 mh1
        #pragma unroll
        for (int m = 0; m < 3; m++)
            afr[m] = *(const bf16x8*)(L + aBase + (3 + m) * 2048 + csw1);
        WAITL();
        #pragma unroll
        for (int m = 0; m < 3; m++)
            #pragma unroll
            for (int n = 0; n < 2; n++)
                acc[3 + m][n] = __builtin_amdgcn_mfma_f32_16x16x32_bf16(afr[m], bfr[n], acc[3 + m][n], 0, 0, 0);
    }

    // ---- epilogue: BN+ReLU fused, bf16 store ----
    #pragma unroll
    for (int n = 0; n < 2; n++) {
        int col = n0 + wc * 32 + n * 16 + fr;
        float sc = scale[col], sh = shift[col];
        #pragma unroll
        for (int m = 0; m < 6; m++) {
            long rbase = m0 + wr * 96 + m * 16 + ls * 4;
            #pragma unroll
            for (int j = 0; j < 4; j++) {
                float v = acc[m][n][j] * sc + sh;
                v = v > 0.f ? v : 0.f;
                xout[(rbase + j) * COUT + col] = f2bf(v);
            }
        }
    }
}

// --- K2: 1x1 conv (256->25) + bias + softmax -> kmaps [pix][25] ----------
__global__ __launch_bounds__(256) void conv2_softmax(
        const unsigned short* __restrict__ x, const float* __restrict__ w2,
        const float* __restrict__ b2, float* __restrict__ kmaps) {
    __shared__ float w2s[NORD * 256];
    __shared__ float b2s[NORD];
    for (int i = threadIdx.x; i < NORD * 256; i += 256) w2s[i] = w2[i];
    if (threadIdx.x < NORD) b2s[threadIdx.x] = b2[threadIdx.x];
    __syncthreads();
    long pix = (long)blockIdx.x * 256 + threadIdx.x;
    float acc[NORD];
    #pragma unroll
    for (int o = 0; o < NORD; o++) acc[o] = b2s[o];
    const unsigned short* xr = x + pix * COUT;
    for (int kc = 0; kc < 32; kc++) {
        uint4 raw = *(const uint4*)(xr + kc * 8);
        float xf[8];
        xf[0] = bf_lo(raw.x); xf[1] = bf_hi(raw.x);
        xf[2] = bf_lo(raw.y); xf[3] = bf_hi(raw.y);
        xf[4] = bf_lo(raw.z); xf[5] = bf_hi(raw.z);
        xf[6] = bf_lo(raw.w); xf[7] = bf_hi(raw.w);
        #pragma unroll
        for (int o = 0; o < NORD; o++) {
            const float* wrow = &w2s[o * 256 + kc * 8];
            float4 wa = *(const float4*)(wrow);
            float4 wb = *(const float4*)(wrow + 4);
            acc[o] += xf[0] * wa.x + xf[1] * wa.y + xf[2] * wa.z + xf[3] * wa.w
                    + xf[4] * wb.x + xf[5] * wb.y + xf[6] * wb.z + xf[7] * wb.w;
        }
    }
    float mx = acc[0];
    #pragma unroll
    for (int o = 1; o < NORD; o++) mx = fmaxf(mx, acc[o]);
    float s = 0.f;
    #pragma unroll
    for (int o = 0; o < NORD; o++) { acc[o] = expf(acc[o] - mx); s += acc[o]; }
    float inv = 1.f / s;
    float* kout = kmaps + pix * NORD;
    #pragma unroll
    for (int o = 0; o < NORD; o++) kout[o] = acc[o] * inv;
}

// --- K3: 25-tap weighted propagation -------------------------------------
__global__ __launch_bounds__(576) void propagate(
        const float* __restrict__ src, const float* __restrict__ kmaps,
        float* __restrict__ out) {
    __shared__ float sm[28 * 28];
    int b  = blockIdx.y;
    int cg = blockIdx.x;
    int tid = threadIdx.x;
    int y = tid / 24, x = tid - y * 24;
    float km[NORD];
    const float* kp = kmaps + ((long)b * NPIX + tid) * NORD;
    #pragma unroll
    for (int o = 0; o < NORD; o++) km[o] = kp[o];
    for (int c = 0; c < 16; c++) {
        int cc = cg * 16 + c;
        const float* sp = src + ((long)b * CIN + cc) * NPIX;
        __syncthreads();
        for (int t = tid; t < 28 * 28; t += 576) {
            int yy = t / 28, xx = t - yy * 28;
            float v = 0.f;
            if (yy >= 2 && yy < 26 && xx >= 2 && xx < 26)
                v = sp[(yy - 2) * 24 + (xx - 2)];
            sm[t] = v;
        }
        __syncthreads();
        float a = 0.f;
        #pragma unroll
        for (int o = 0; o < NORD; o++) {
            int dy = o / 5 - 2, dx = o % 5 - 2;
            a += km[o] * sm[(y + 2 + dy) * 28 + (x + 2 + dx)];
        }
        out[((long)b * CIN + cc) * NPIX + tid] = a;
    }
}

extern "C" void kernel_launch(void* const* d_in, const int* in_sizes, int n_in,
                              void* d_out, int out_size, void* d_ws, size_t ws_size,
                              hipStream_t stream) {
    const float* src = (const float*)d_in[0];
    const float* det = (const float*)d_in[1];
    const float* w1  = (const float*)d_in[2];
    const float* b1  = (const float*)d_in[3];
    const float* gam = (const float*)d_in[4];
    const float* bet = (const float*)d_in[5];
    const float* mu  = (const float*)d_in[6];
    const float* var = (const float*)d_in[7];
    const float* w2  = (const float*)d_in[8];
    const float* b2  = (const float*)d_in[9];
    float* out = (float*)d_out;

    char* ws = (char*)d_ws;
    size_t off = 0;
    unsigned short* apad = (unsigned short*)(ws + off); off += (size_t)BATCH * HP * WP * CCAT * 2;
    unsigned short* bt   = (unsigned short*)(ws + off); off += (size_t)COUT * KDIM * 2;
    unsigned short* xbuf = (unsigned short*)(ws + off); off += (size_t)MDIM * COUT * 2;
    float* kmaps = (float*)(ws + off); off += (size_t)MDIM * NORD * 4;
    float* scale = (float*)(ws + off); off += 1024;
    float* shift = (float*)(ws + off); off += 1024;

    zero_halo<<<3200, 256, 0, stream>>>(apad);
    prep_transpose<<<dim3(3, 8, BATCH), 256, 0, stream>>>(src, det, apad);
    prep_w<<<4608, 256, 0, stream>>>(w1, b1, gam, bet, mu, var, bt, scale, shift);
    conv1_gemm<<<768, 512, 0, stream>>>(apad, bt, scale, shift, xbuf);
    conv2_softmax<<<288, 256, 0, stream>>>(xbuf, w2, b2, kmaps);
    propagate<<<dim3(16, BATCH), 576, 0, stream>>>(src, kmaps, out);
}

// Round 5
// 345.389 us; speedup vs baseline: 2.3867x; 1.0386x over previous
//
#include <hip/hip_runtime.h>
#include <hip/hip_bf16.h>
#include <stdint.h>

#define BATCH 128
#define CIN   256
#define CCAT  512
#define HH    24
#define WW    24
#define HP    26
#define WP    26
#define COUT  256
#define KDIM  4608   // 9*512
#define NPIX  576    // 24*24
#define MDIM  73728  // 128*576
#define NORD  25

typedef __attribute__((ext_vector_type(8))) short bf16x8;
typedef __attribute__((ext_vector_type(4))) float f32x4;

__device__ __forceinline__ unsigned short f2bf(float v) {
    union { float f; unsigned u; } x; x.f = v;
    unsigned r = x.u + 0x7fffu + ((x.u >> 16) & 1u);
    return (unsigned short)(r >> 16);
}
__device__ __forceinline__ float bf_lo(unsigned w) {
    union { unsigned u; float f; } x; x.u = w << 16; return x.f;
}
__device__ __forceinline__ float bf_hi(unsigned w) {
    union { unsigned u; float f; } x; x.u = w & 0xffff0000u; return x.f;
}

__device__ __forceinline__ void async_copy16(const void* gsrc, void* ldst) {
    __builtin_amdgcn_global_load_lds(
        (const __attribute__((address_space(1))) unsigned int*)gsrc,
        (__attribute__((address_space(3))) unsigned int*)ldst, 16, 0, 0);
}

// --- K0a: coalesced NCHW fp32 -> padded NHWC bf16 via LDS transpose ------
#define PTILE 192
#define LSTR  72
__global__ __launch_bounds__(256) void prep_transpose(
        const float* __restrict__ src, const float* __restrict__ det,
        unsigned short* __restrict__ apad) {
    __shared__ unsigned short lds[PTILE * LSTR];
    int pt = blockIdx.x;
    int cg = blockIdx.y;
    int b  = blockIdx.z;
    int c0 = cg * 64;
    int p0 = pt * PTILE;
    const float* inp = (c0 < CIN)
        ? (src + ((long)b * CIN + c0) * NPIX)
        : (det + ((long)b * CIN + (c0 - CIN)) * NPIX);
    int tid = threadIdx.x;

    #pragma unroll
    for (int it = 0; it < 12; it++) {
        int l  = it * 256 + tid;
        int cq = l / PTILE;
        int px = l - cq * PTILE;
        const float* pb = inp + (long)cq * 4 * NPIX + p0 + px;
        unsigned short v0 = f2bf(pb[0 * NPIX]);
        unsigned short v1 = f2bf(pb[1 * NPIX]);
        unsigned short v2 = f2bf(pb[2 * NPIX]);
        unsigned short v3 = f2bf(pb[3 * NPIX]);
        uint2 w;
        w.x = (unsigned)v0 | ((unsigned)v1 << 16);
        w.y = (unsigned)v2 | ((unsigned)v3 << 16);
        *(uint2*)&lds[px * LSTR + cq * 4] = w;
    }
    __syncthreads();

    #pragma unroll
    for (int it = 0; it < 6; it++) {
        int l   = it * 256 + tid;
        int px  = l >> 3;
        int ch8 = l & 7;
        uint4 w = *(const uint4*)&lds[px * LSTR + ch8 * 8];
        int p  = p0 + px;
        int y  = p / WW, x = p - y * WW;
        long o = (((long)b * HP + (y + 1)) * WP + (x + 1)) * CCAT + c0 + ch8 * 8;
        *(uint4*)(apad + o) = w;
    }
}

// --- K0a': zero the 1-wide halo ------------------------------------------
__global__ __launch_bounds__(256) void zero_halo(unsigned short* __restrict__ apad) {
    int t = blockIdx.x * 256 + threadIdx.x;
    int ch8 = t & 63;
    int r   = t >> 6;
    int hp  = r % 100;
    int b   = r / 100;
    int y, x;
    if (hp < 26)      { y = 0;       x = hp; }
    else if (hp < 52) { y = 25;      x = hp - 26; }
    else if (hp < 76) { y = hp - 51; x = 0; }
    else              { y = hp - 75; x = 25; }
    long o = (((long)b * HP + y) * WP + x) * CCAT + ch8 * 8;
    *(uint4*)(apad + o) = (uint4){0u, 0u, 0u, 0u};
}

// --- K0b: w1 OIHW -> B^T [256][4608] bf16; fold BN+bias ------------------
__global__ __launch_bounds__(256) void prep_w(
        const float* __restrict__ w1, const float* __restrict__ b1,
        const float* __restrict__ gam, const float* __restrict__ bet,
        const float* __restrict__ mu, const float* __restrict__ var,
        unsigned short* __restrict__ bt,
        float* __restrict__ scale, float* __restrict__ shift) {
    int idx = blockIdx.x * 256 + threadIdx.x;
    if (idx < COUT * KDIM) {
        int n = idx / KDIM;
        int k = idx - n * KDIM;
        int s = k >> 9;
        int ci = k & 511;
        int ky = s / 3, kx = s - ky * 3;
        float v = w1[(((long)n * 512 + ci) * 3 + ky) * 3 + kx];
        bt[idx] = f2bf(v);
    }
    if (blockIdx.x == 0 && threadIdx.x < COUT) {
        int c = threadIdx.x;
        float inv = gam[c] * rsqrtf(var[c] + 1e-5f);
        scale[c] = inv;
        shift[c] = (b1[c] - mu[c]) * inv + bet[c];
    }
}

// --- K1: conv1 implicit GEMM, 288x256 tile, 8 waves, 6-phase counted-vmcnt
// grid = 256 blocks = exactly 1/CU, one dispatch wave, zero tail.
// LDS = 2 buf x (A 288x64 + B 256x64) bf16 = 136 KiB.
// Staging per K-tile: 4 B instr + 4.5 A instr (half-instr on waves 0-3).
// Ledger: at p0 issue 4 B(t+1) then vmcnt(4) -> drains all of tile t
// (9 slices on waves 0-3, 8 on waves 4-7), leaves the 4 new B in flight.
#define BUF_SH  34816   // shorts per buffer: 288*64 + 256*64
#define ABUF_SH 18432   // 288*64 shorts
#define STAGE_A(j, nb, soff) \
    async_copy16(apad + aSrc[j] + (soff), (void*)&lds[(nb)*BUF_SH + (j)*4096 + w*512])
#define STAGE_B(j, nb, koff) \
    async_copy16(bt + bSrc[j] + (koff), (void*)&lds[(nb)*BUF_SH + ABUF_SH + (j)*4096 + w*512])
#define BAR()  __builtin_amdgcn_s_barrier()
#define WAITV4() { asm volatile("s_waitcnt vmcnt(4)" ::: "memory"); }
#define WAITV0() { asm volatile("s_waitcnt vmcnt(0)" ::: "memory"); }
#define WAITL()  { asm volatile("s_waitcnt lgkmcnt(0)" ::: "memory"); __builtin_amdgcn_sched_barrier(0); }

#define AFRAGS(mh, csw) { \
    _Pragma("unroll") \
    for (int m = 0; m < 3; m++) \
        afr[m] = *(const bf16x8*)(L + aBase + ((mh) * 3 + m) * 2048 + (csw)); }
#define BFRAGS(csw) { \
    _Pragma("unroll") \
    for (int n = 0; n < 4; n++) \
        bfr[n] = *(const bf16x8*)(L + bBase + n * 2048 + (csw)); }
#define DOMFMA(mh) { \
    __builtin_amdgcn_s_setprio(1); \
    _Pragma("unroll") \
    for (int m = 0; m < 3; m++) \
        _Pragma("unroll") \
        for (int n = 0; n < 4; n++) \
            acc[(mh) * 3 + m][n] = __builtin_amdgcn_mfma_f32_16x16x32_bf16( \
                afr[m], bfr[n], acc[(mh) * 3 + m][n], 0, 0, 0); \
    __builtin_amdgcn_s_setprio(0); }

__global__ __launch_bounds__(512, 2) void conv1_gemm(
        const unsigned short* __restrict__ apad,
        const unsigned short* __restrict__ bt,
        const float* __restrict__ scale, const float* __restrict__ shift,
        unsigned short* __restrict__ xout) {
    __shared__ unsigned short lds[2 * BUF_SH];   // 139,264 B
    const int tid  = threadIdx.x;
    const int w    = tid >> 6;
    const int lane = tid & 63;
    const int wr = w >> 2, wc = w & 3;      // 2M x 4N waves (144x64 each)
    const int fr = lane & 15, ls = lane >> 4;
    const long m0 = (long)blockIdx.x * 288;

    // staging sources: instr j covers tile rows j*64..j*64+63 (A j=4: 32
    // rows, waves 0-3 only); 8 thr/row, 16B/thr, slot pre-swizzled so the
    // linear gload_lds fill lands XOR-swizzled.
    const int rowq = tid >> 3;                  // 0..63
    const int sl   = (tid & 7) ^ (rowq & 7);    // swizzled 16B slot
    long aSrc[5], bSrc[4];
    #pragma unroll
    for (int j = 0; j < 5; j++) {
        int r = (j == 4) ? (256 + (rowq & 31)) : (j * 64 + rowq);
        long m = m0 + r;
        int b  = (int)(m / NPIX);
        int rr = (int)(m - (long)b * NPIX);
        int y = rr / WW, x = rr - y * WW;
        aSrc[j] = (((long)b * HP + y) * WP + x) * (long)CCAT + sl * 8;
    }
    #pragma unroll
    for (int j = 0; j < 4; j++)
        bSrc[j] = (long)(j * 64 + rowq) * KDIM + sl * 8;

    // fragment read offsets (bytes): row*128 + ((kk*4+ls)^(fr&7))*16
    const int rb   = fr & 7;
    const int csw0 = ((ls    ) ^ rb) << 4;
    const int csw1 = ((ls + 4) ^ rb) << 4;
    const int aBase = (wr * 144 + fr) * 128;            // + msub*2048
    const int bBase = ABUF_SH * 2 + (wc * 64 + fr) * 128;  // + n*2048

    f32x4 acc[9][4];
    #pragma unroll
    for (int i = 0; i < 9; i++)
        #pragma unroll
        for (int j = 0; j < 4; j++) acc[i][j] = (f32x4){0.f, 0.f, 0.f, 0.f};

    // prologue: stage tile 0 into buf 0 (9 slices waves 0-3, 8 waves 4-7)
    STAGE_B(0, 0, 0); STAGE_B(1, 0, 0); STAGE_B(2, 0, 0); STAGE_B(3, 0, 0);
    STAGE_A(0, 0, 0); STAGE_A(1, 0, 0); STAGE_A(2, 0, 0); STAGE_A(3, 0, 0);
    if (tid < 256) STAGE_A(4, 0, 0);

    bf16x8 afr[3], bfr[4];
    int nb = 0;
    for (int kt = 0; kt < 71; kt++) {
        const int ktn = kt + 1;
        const int seg = ktn >> 3;
        const int ky = seg / 3, kx = seg - ky * 3;
        const long soff = (long)(ky * WP + kx) * CCAT + (ktn & 7) * 64;
        const long koff = (long)ktn * 64;
        const int pb = nb ^ 1;
        const char* L = (const char*)lds + nb * (BUF_SH * 2);

        // ---- p0: kk=0, mh=0 ----
        STAGE_B(0, pb, koff); STAGE_B(1, pb, koff);
        STAGE_B(2, pb, koff); STAGE_B(3, pb, koff);
        WAITV4();           // tile t fully landed; 4 B(t+1) in flight
        BAR();
        BFRAGS(csw0); AFRAGS(0, csw0);
        WAITL();
        DOMFMA(0);
        BAR();

        // ---- p1: kk=0, mh=1 ----
        AFRAGS(1, csw0);
        STAGE_A(0, pb, soff); STAGE_A(1, pb, soff);
        WAITL();
        DOMFMA(1);
        BAR();

        // ---- p2: kk=0, mh=2 ----
        AFRAGS(2, csw0);
        STAGE_A(2, pb, soff); STAGE_A(3, pb, soff);
        if (tid < 256) STAGE_A(4, pb, soff);
        WAITL();
        DOMFMA(2);
        BAR();

        // ---- p3: kk=1, mh=0 ----
        BFRAGS(csw1); AFRAGS(0, csw1);
        WAITL();
        DOMFMA(0);
        BAR();

        // ---- p4: kk=1, mh=1 ----
        AFRAGS(1, csw1);
        WAITL();
        DOMFMA(1);
        BAR();

        // ---- p5: kk=1, mh=2 ----
        AFRAGS(2, csw1);
        WAITL();
        DOMFMA(2);
        BAR();

        nb ^= 1;
    }

    // ---- peeled last tile (kt=71), no prefetch, no barriers needed ----
    {
        const char* L = (const char*)lds + nb * (BUF_SH * 2);
        WAITV0();
        BAR();
        BFRAGS(csw0); AFRAGS(0, csw0); WAITL(); DOMFMA(0);
        AFRAGS(1, csw0);               WAITL(); DOMFMA(1);
        AFRAGS(2, csw0);               WAITL(); DOMFMA(2);
        BFRAGS(csw1); AFRAGS(0, csw1); WAITL(); DOMFMA(0);
        AFRAGS(1, csw1);               WAITL(); DOMFMA(1);
        AFRAGS(2, csw1);               WAITL(); DOMFMA(2);
    }

    // ---- epilogue: BN+ReLU fused, bf16 store ----
    #pragma unroll
    for (int n = 0; n < 4; n++) {
        int col = wc * 64 + n * 16 + fr;
        float sc = scale[col], sh = shift[col];
        #pragma unroll
        for (int m = 0; m < 9; m++) {
            long rbase = m0 + wr * 144 + m * 16 + ls * 4;
            #pragma unroll
            for (int j = 0; j < 4; j++) {
                float v = acc[m][n][j] * sc + sh;
                v = v > 0.f ? v : 0.f;
                xout[(rbase + j) * COUT + col] = f2bf(v);
            }
        }
    }
}

// --- K2: 1x1 conv (256->25) + bias + softmax -> kmaps PLANAR [25][M] -----
__global__ __launch_bounds__(256) void conv2_softmax(
        const unsigned short* __restrict__ x, const float* __restrict__ w2,
        const float* __restrict__ b2, float* __restrict__ kmaps) {
    __shared__ float w2s[NORD * 256];
    __shared__ float b2s[NORD];
    for (int i = threadIdx.x; i < NORD * 256; i += 256) w2s[i] = w2[i];
    if (threadIdx.x < NORD) b2s[threadIdx.x] = b2[threadIdx.x];
    __syncthreads();
    long pix = (long)blockIdx.x * 256 + threadIdx.x;
    float acc[NORD];
    #pragma unroll
    for (int o = 0; o < NORD; o++) acc[o] = b2s[o];
    const unsigned short* xr = x + pix * COUT;
    for (int kc = 0; kc < 32; kc++) {
        uint4 raw = *(const uint4*)(xr + kc * 8);
        float xf[8];
        xf[0] = bf_lo(raw.x); xf[1] = bf_hi(raw.x);
        xf[2] = bf_lo(raw.y); xf[3] = bf_hi(raw.y);
        xf[4] = bf_lo(raw.z); xf[5] = bf_hi(raw.z);
        xf[6] = bf_lo(raw.w); xf[7] = bf_hi(raw.w);
        #pragma unroll
        for (int o = 0; o < NORD; o++) {
            const float* wrow = &w2s[o * 256 + kc * 8];
            float4 wa = *(const float4*)(wrow);
            float4 wb = *(const float4*)(wrow + 4);
            acc[o] += xf[0] * wa.x + xf[1] * wa.y + xf[2] * wa.z + xf[3] * wa.w
                    + xf[4] * wb.x + xf[5] * wb.y + xf[6] * wb.z + xf[7] * wb.w;
        }
    }
    float mx = acc[0];
    #pragma unroll
    for (int o = 1; o < NORD; o++) mx = fmaxf(mx, acc[o]);
    float s = 0.f;
    #pragma unroll
    for (int o = 0; o < NORD; o++) { acc[o] = expf(acc[o] - mx); s += acc[o]; }
    float inv = 1.f / s;
    #pragma unroll
    for (int o = 0; o < NORD; o++) kmaps[(long)o * MDIM + pix] = acc[o] * inv;
}

// --- K3: 25-tap weighted propagation; planar kmaps, km loaded once -------
// block = (cg in [0,4), b); 64 channels/block, 4 planes staged per round.
__global__ __launch_bounds__(576) void propagate(
        const float* __restrict__ src, const float* __restrict__ kmaps,
        float* __restrict__ out) {
    __shared__ float sm[4][28 * 28];
    int b  = blockIdx.y;
    int cg = blockIdx.x;
    int tid = threadIdx.x;
    int y = tid / 24, x = tid - y * 24;
    long pixg = (long)b * NPIX + tid;
    float km[NORD];
    #pragma unroll
    for (int o = 0; o < NORD; o++) km[o] = kmaps[(long)o * MDIM + pixg];
    for (int r = 0; r < 16; r++) {
        int cbase = cg * 64 + r * 4;
        __syncthreads();
        for (int t = tid; t < 4 * 784; t += 576) {
            int cp = t / 784, u = t - cp * 784;
            int yy = u / 28, xx = u - yy * 28;
            float v = 0.f;
            if (yy >= 2 && yy < 26 && xx >= 2 && xx < 26)
                v = src[((long)b * CIN + cbase + cp) * NPIX + (yy - 2) * 24 + (xx - 2)];
            sm[cp][u] = v;
        }
        __syncthreads();
        #pragma unroll
        for (int cp = 0; cp < 4; cp++) {
            float a = 0.f;
            #pragma unroll
            for (int o = 0; o < NORD; o++) {
                int dy = o / 5 - 2, dx = o % 5 - 2;
                a += km[o] * sm[cp][(y + 2 + dy) * 28 + (x + 2 + dx)];
            }
            out[((long)b * CIN + cbase + cp) * NPIX + tid] = a;
        }
    }
}

extern "C" void kernel_launch(void* const* d_in, const int* in_sizes, int n_in,
                              void* d_out, int out_size, void* d_ws, size_t ws_size,
                              hipStream_t stream) {
    const float* src = (const float*)d_in[0];
    const float* det = (const float*)d_in[1];
    const float* w1  = (const float*)d_in[2];
    const float* b1  = (const float*)d_in[3];
    const float* gam = (const float*)d_in[4];
    const float* bet = (const float*)d_in[5];
    const float* mu  = (const float*)d_in[6];
    const float* var = (const float*)d_in[7];
    const float* w2  = (const float*)d_in[8];
    const float* b2  = (const float*)d_in[9];
    float* out = (float*)d_out;

    char* ws = (char*)d_ws;
    size_t off = 0;
    unsigned short* apad = (unsigned short*)(ws + off); off += (size_t)BATCH * HP * WP * CCAT * 2;
    unsigned short* bt   = (unsigned short*)(ws + off); off += (size_t)COUT * KDIM * 2;
    unsigned short* xbuf = (unsigned short*)(ws + off); off += (size_t)MDIM * COUT * 2;
    float* kmaps = (float*)(ws + off); off += (size_t)MDIM * NORD * 4;
    float* scale = (float*)(ws + off); off += 1024;
    float* shift = (float*)(ws + off); off += 1024;

    zero_halo<<<3200, 256, 0, stream>>>(apad);
    prep_transpose<<<dim3(3, 8, BATCH), 256, 0, stream>>>(src, det, apad);
    prep_w<<<4608, 256, 0, stream>>>(w1, b1, gam, bet, mu, var, bt, scale, shift);
    conv1_gemm<<<256, 512, 0, stream>>>(apad, bt, scale, shift, xbuf);
    conv2_softmax<<<288, 256, 0, stream>>>(xbuf, w2, b2, kmaps);
    propagate<<<dim3(4, BATCH), 576, 0, stream>>>(src, kmaps, out);
}